// Round 5
// baseline (399.398 us; speedup 1.0000x reference)
//
#include <hip/hip_runtime.h>
#include <hip/hip_cooperative_groups.h>
#include <math.h>

namespace cg = cooperative_groups;

#define NB 32
#define NC 256
#define SH 56
#define SW 56
#define HW 3136      // 56*56
#define HW4 784      // HW/4
#define PERB4 (NC * HW4)     // 200704 float4 per image
#define GRID 784
#define TOTAL4 (NB * PERB4)  // 6,422,528 float4 == GRID*256*32 exactly

// One cooperative kernel, three phases separated by grid.sync():
//  A: channel max/mean reduce  (identical pattern to the R1 k_reduce)
//  B: 7x7 conv + folded BN + sigmoid -> gate (blocks 0..391 active)
//  C: out = x * gate, linear grid-stride (identical pattern to R1 k_mul)
__global__ __launch_bounds__(256, 4) void k_fused(const float4* __restrict__ x,
                                                  const float* __restrict__ cw,
                                                  const float* __restrict__ gamma,
                                                  const float* __restrict__ beta,
                                                  const float* __restrict__ rmean,
                                                  const float* __restrict__ rvar,
                                                  float4* __restrict__ out,
                                                  float* __restrict__ mx_p,
                                                  float* __restrict__ av_p,
                                                  float* __restrict__ gate_p) {
    cg::grid_group grid = cg::this_grid();
    __shared__ __align__(16) float shraw[2048];      // 8 KB, reused per phase
    const int tid = threadIdx.x;
    const int bid = blockIdx.x;

    // ---------------- Phase A: reduce ----------------
    {
        float4* smax = (float4*)shraw;               // [8][32]
        float4* ssum = smax + 256;                   // [8][32]
        const int pos = tid & 31;
        const int cgi = tid >> 5;
        const unsigned g = (unsigned)bid * 32u + (unsigned)pos;  // global float4 pos
        const int b  = (int)(g / HW4);
        const int p4 = (int)(g - (unsigned)b * HW4);
        const float4* base = x + (size_t)b * PERB4 + p4 + (size_t)(cgi * 32) * HW4;

        const float NEG = -__builtin_inff();
        float4 vmax = make_float4(NEG, NEG, NEG, NEG);
        float4 vsum = make_float4(0.f, 0.f, 0.f, 0.f);
        #pragma unroll 8
        for (int c = 0; c < 32; ++c) {
            float4 v = base[(size_t)c * HW4];
            vmax.x = fmaxf(vmax.x, v.x); vmax.y = fmaxf(vmax.y, v.y);
            vmax.z = fmaxf(vmax.z, v.z); vmax.w = fmaxf(vmax.w, v.w);
            vsum.x += v.x; vsum.y += v.y; vsum.z += v.z; vsum.w += v.w;
        }
        smax[cgi * 32 + pos] = vmax;
        ssum[cgi * 32 + pos] = vsum;
        __syncthreads();
        if (tid < 32) {
            float4 m = smax[tid];
            float4 s = ssum[tid];
            #pragma unroll
            for (int q = 1; q < 8; ++q) {
                float4 mm = smax[q * 32 + tid];
                float4 ss = ssum[q * 32 + tid];
                m.x = fmaxf(m.x, mm.x); m.y = fmaxf(m.y, mm.y);
                m.z = fmaxf(m.z, mm.z); m.w = fmaxf(m.w, mm.w);
                s.x += ss.x; s.y += ss.y; s.z += ss.z; s.w += ss.w;
            }
            const float r = 1.0f / 256.0f;
            s.x *= r; s.y *= r; s.z *= r; s.w *= r;
            const unsigned go = (unsigned)bid * 32u + (unsigned)tid;
            ((float4*)mx_p)[go] = m;
            ((float4*)av_p)[go] = s;
        }
    }
    __threadfence();
    grid.sync();

    // ---------------- Phase B: conv + BN + sigmoid ----------------
    {
        float* sw = shraw;                            // [99]
        const float inv = gamma[0] * rsqrtf(rvar[0] + 1e-5f);
        if (tid < 98) sw[tid] = cw[tid] * inv;
        if (tid == 0) sw[98] = beta[0] - rmean[0] * inv;
        __syncthreads();

        const int idx = bid * 256 + tid;
        if (idx < NB * HW) {
            const int b = idx / HW;
            const int p = idx - b * HW;
            const int h = p / SW;
            const int w = p - h * SW;
            const float* mrow = mx_p + (size_t)b * HW;
            const float* arow = av_p + (size_t)b * HW;
            float acc = sw[98];
            #pragma unroll
            for (int kh = 0; kh < 7; ++kh) {
                const int hh = h + kh - 3;
                if (hh < 0 || hh >= SH) continue;
                #pragma unroll
                for (int kw = 0; kw < 7; ++kw) {
                    const int ww = w + kw - 3;
                    if (ww < 0 || ww >= SW) continue;
                    const int q = hh * SW + ww;
                    acc += mrow[q] * sw[kh * 7 + kw] + arow[q] * sw[49 + kh * 7 + kw];
                }
            }
            gate_p[idx] = 1.0f / (1.0f + expf(-acc));
        }
    }
    __threadfence();
    grid.sync();

    // ---------------- Phase C: multiply ----------------
    {
        const float4* gate4 = (const float4*)gate_p;
        unsigned v = (unsigned)bid * 256u + (unsigned)tid;
        #pragma unroll 4
        for (int i = 0; i < 32; ++i, v += (unsigned)(GRID * 256)) {
            const unsigned row = v / HW4;             // b*NC + c (magic-mul)
            const unsigned p4  = v - row * HW4;
            const unsigned b   = row >> 8;
            const float4 g  = gate4[b * HW4 + p4];
            const float4 xv = x[v];
            out[v] = make_float4(xv.x * g.x, xv.y * g.y, xv.z * g.z, xv.w * g.w);
        }
    }
}

extern "C" void kernel_launch(void* const* d_in, const int* in_sizes, int n_in,
                              void* d_out, int out_size, void* d_ws, size_t ws_size,
                              hipStream_t stream) {
    const float4* x4   = (const float4*)d_in[0];
    const float* cw    = (const float*)d_in[1];
    const float* gamma = (const float*)d_in[2];
    const float* beta  = (const float*)d_in[3];
    const float* rmean = (const float*)d_in[4];
    const float* rvar  = (const float*)d_in[5];
    float4* out4 = (float4*)d_out;

    // Workspace layout (floats): mx [B*HW] | av [B*HW] | gate [B*HW]
    float* mx_p   = (float*)d_ws;
    float* av_p   = mx_p + (size_t)NB * HW;
    float* gate_p = av_p + (size_t)NB * HW;

    void* args[] = { (void*)&x4, (void*)&cw, (void*)&gamma, (void*)&beta,
                     (void*)&rmean, (void*)&rvar, (void*)&out4,
                     (void*)&mx_p, (void*)&av_p, (void*)&gate_p };
    hipLaunchCooperativeKernel((const void*)k_fused, dim3(GRID), dim3(256),
                               args, 0, stream);
}

// Round 6
// 63.848 us; speedup vs baseline: 6.2555x; 6.2555x over previous
//
#include <hip/hip_runtime.h>
#include <math.h>

#define NB 32
#define NC 256
#define SH 56
#define SW 56
#define HW 3136      // 56*56
#define HW4 784      // float4 per image plane
#define PERB4 (NC * HW4)   // 200704 float4 per image
#define NCG 8              // channel groups (32 ch each)

__device__ __forceinline__ float4 max4(float4 a, float4 b) {
    return make_float4(fmaxf(a.x,b.x), fmaxf(a.y,b.y), fmaxf(a.z,b.z), fmaxf(a.w,b.w));
}
__device__ __forceinline__ float4 add4(float4 a, float4 b) {
    return make_float4(a.x+b.x, a.y+b.y, a.z+b.z, a.w+b.w);
}

// ---------------------------------------------------------------------------
// Kernel 1 (linear reduce): grid 512 = (b, cg, half). Each block streams a
// CONTIGUOUS-per-channel 200 KB slab (32 ch x 392 float4 half-plane) with
// register accumulators, writes per-cgroup partial max/sum [512][784]f4 pair.
// Per wave, every load is a 1 KB contiguous segment; block scan is monotone.
// ---------------------------------------------------------------------------
__global__ __launch_bounds__(256) void k_reduce_lin(const float4* __restrict__ x,
                                                    float4* __restrict__ pmax,
                                                    float4* __restrict__ psum) {
    const int tid  = threadIdx.x;
    const int bid  = blockIdx.x;          // ((b*NCG)+cg)*2 + half
    const int half = bid & 1;
    const int bcg  = bid >> 1;            // b*NCG + cg
    const float4* base = x + (size_t)bcg * (32 * HW4) + half * 392;

    const float NEG = -__builtin_inff();
    float4 m0 = make_float4(NEG,NEG,NEG,NEG), s0 = make_float4(0,0,0,0);
    float4 m1 = m0, s1 = s0;
    #pragma unroll 4
    for (int c = 0; c < 32; ++c) {
        const float4 v0 = base[c * HW4 + tid];
        m0 = max4(m0, v0); s0 = add4(s0, v0);
        if (tid < 136) {                  // 392 = 256 + 136 (ragged tail)
            const float4 v1 = base[c * HW4 + 256 + tid];
            m1 = max4(m1, v1); s1 = add4(s1, v1);
        }
    }
    const size_t obase = (size_t)bcg * HW4 + half * 392;
    pmax[obase + tid] = m0;
    psum[obase + tid] = s0;
    if (tid < 136) {
        pmax[obase + 256 + tid] = m1;
        psum[obase + 256 + tid] = s1;
    }
}

// ---------------------------------------------------------------------------
// Kernel 2 (combine + conv + BN + sigmoid + multiply), grid 896 = (b, rp):
//  P0: 8-way combine of partials for halo rows [2rp-3, 2rp+4] -> LDS smx/sav
//  P1: 7x7 conv from LDS + folded BN + sigmoid -> sgate (112 px)
//  P2: stream 256 ch x 28 float4 of x for rows {2rp,2rp+1}, multiply, store.
// ---------------------------------------------------------------------------
__global__ __launch_bounds__(256) void k_gate_mul(const float4* __restrict__ pmax,
                                                  const float4* __restrict__ psum,
                                                  const float* __restrict__ cw,
                                                  const float* __restrict__ gamma,
                                                  const float* __restrict__ beta,
                                                  const float* __restrict__ rmean,
                                                  const float* __restrict__ rvar,
                                                  const float4* __restrict__ x,
                                                  float4* __restrict__ out) {
    __shared__ float sw[99];
    __shared__ __align__(16) float smx[8 * SW];   // 8 halo rows, combined max
    __shared__ __align__(16) float sav[8 * SW];   // 8 halo rows, combined mean
    __shared__ float4 sgate4[28];

    const int tid = threadIdx.x;
    const int b  = blockIdx.x / 28;
    const int rp = blockIdx.x - b * 28;

    const float inv = gamma[0] * rsqrtf(rvar[0] + 1e-5f);
    if (tid < 98) sw[tid] = cw[tid] * inv;
    if (tid == 0) sw[98] = beta[0] - rmean[0] * inv;

    // ---- P0: combine 8 cgroup partials over halo rows ----
    const int r0  = 2 * rp - 3;                 // first conv-tap row (may be <0)
    const int rlo = r0 > 0 ? r0 : 0;
    const int rhi = (2 * rp + 4) < (SH - 1) ? (2 * rp + 4) : (SH - 1);
    const int n4  = (rhi - rlo + 1) * 14;       // float4 to stage (<= 112)
    const int sh4 = (rlo - r0) * 14;            // LDS slot offset

    if (tid < n4) {                             // threads 0..111: max combine
        const size_t pb = (size_t)(b * NCG) * HW4 + rlo * 14 + tid;
        float4 m = pmax[pb];
        #pragma unroll
        for (int cg = 1; cg < NCG; ++cg) m = max4(m, pmax[pb + (size_t)cg * HW4]);
        ((float4*)smx)[sh4 + tid] = m;
    } else if (tid >= 128 && tid - 128 < n4) {  // threads 128..239: sum combine
        const int t = tid - 128;
        const size_t pb = (size_t)(b * NCG) * HW4 + rlo * 14 + t;
        float4 s = psum[pb];
        #pragma unroll
        for (int cg = 1; cg < NCG; ++cg) s = add4(s, psum[pb + (size_t)cg * HW4]);
        const float r = 1.0f / 256.0f;
        s.x *= r; s.y *= r; s.z *= r; s.w *= r;
        ((float4*)sav)[sh4 + t] = s;
    }
    __syncthreads();

    // ---- P1: conv + sigmoid for 112 px (rows 2rp, 2rp+1) ----
    if (tid < 112) {
        const int lr = tid >= 56 ? 1 : 0;
        const int w  = tid - lr * 56;
        const int hr = 2 * rp + lr;
        float acc = sw[98];
        #pragma unroll
        for (int kh = 0; kh < 7; ++kh) {
            const int hh = hr + kh - 3;
            if (hh < 0 || hh >= SH) continue;
            const int slot = lr + kh;           // == hh - r0
            #pragma unroll
            for (int kw = 0; kw < 7; ++kw) {
                const int ww = w + kw - 3;
                if (ww < 0 || ww >= SW) continue;
                acc += smx[slot * SW + ww] * sw[kh * 7 + kw]
                     + sav[slot * SW + ww] * sw[49 + kh * 7 + kw];
            }
        }
        ((float*)sgate4)[tid] = 1.0f / (1.0f + expf(-acc));
    }
    __syncthreads();

    // ---- P2: multiply strip (256 ch x 28 float4) ----
    const size_t strip = (size_t)b * PERB4 + (size_t)rp * 28;
    #pragma unroll 4
    for (int it = 0; it < 28; ++it) {
        const unsigned idx = (unsigned)it * 256u + (unsigned)tid;  // 0..7167
        const unsigned c = idx / 28u;
        const unsigned q = idx - c * 28u;
        const size_t off = strip + (size_t)c * HW4 + q;
        const float4 g  = sgate4[q];
        const float4 xv = x[off];
        out[off] = make_float4(xv.x * g.x, xv.y * g.y, xv.z * g.z, xv.w * g.w);
    }
}

extern "C" void kernel_launch(void* const* d_in, const int* in_sizes, int n_in,
                              void* d_out, int out_size, void* d_ws, size_t ws_size,
                              hipStream_t stream) {
    const float* x     = (const float*)d_in[0];
    const float* cw    = (const float*)d_in[1];
    const float* gamma = (const float*)d_in[2];
    const float* beta  = (const float*)d_in[3];
    const float* rmean = (const float*)d_in[4];
    const float* rvar  = (const float*)d_in[5];
    float* out = (float*)d_out;

    // Workspace: pmax [512*784 float4] | psum [512*784 float4]  (12.8 MB)
    float4* pmax = (float4*)d_ws;
    float4* psum = pmax + (size_t)NB * NCG * HW4;

    k_reduce_lin<<<NB * NCG * 2, 256, 0, stream>>>((const float4*)x, pmax, psum);

    k_gate_mul<<<NB * 28, 256, 0, stream>>>(
        pmax, psum, cw, gamma, beta, rmean, rvar,
        (const float4*)x, (float4*)out);
}